// Round 2
// baseline (313.724 us; speedup 1.0000x reference)
//
#include <hip/hip_runtime.h>
#include <math.h>

// ---------------------------------------------------------------------------
// SiameseRPN one-branch, restructured:
//  K0: pad target_feat -> tfp[512][34][34]; transpose w_target -> wT[ci][co][9];
//      zero padded t' buffer tP[256][38][40]
//  K1: blocks 0..255  : fold w_merge_cls into w_template -> WfoldT[4608][128]
//                       (+Bfold[128]) -- reads the 302 MB weight once (HBM-bound)
//      blocks 256..511: 3x3 conv target + BN (+0.1 factor folded) -> tP interior
//                       (VALU-bound, hidden under the fold's bandwidth)
//  K2: Z2 partials: Z2P[n][kc=32][uv=49][eh=128], K-split over ci (16 ci/chunk)
//  K3: merged[n][64][32][32] = sum_{h128,u,v} t'[128n+eh] * Z2[n][eh][uv]
//  K4: 1x1 heads (cls 18, box 36) + paired softmax -> d_out
// Workspace: 3,283,072 floats = 13.2 MB
// ---------------------------------------------------------------------------

#define WS_TFP 0            // 512*34*34      = 591872
#define WS_WT  591872       // 512*256*9      = 1179648
#define WS_TP  1771520      // 256*38*40      = 389120
#define WS_WF  2160640      // 4608*128       = 589824
#define WS_BF  2750464      // 128
#define WS_Z2P 2750592      // 2*32*49*128    = 401408
#define WS_MRG 3152000      // 2*64*32*32     = 131072
// total 3283072 floats

__global__ __launch_bounds__(256) void k0_prep(
    const float* __restrict__ tfeat,   // target_feat 512*32*32
    const float* __restrict__ wtgt,    // w_target 256*512*9
    float* ws)
{
  const int N0 = 591872, N1 = 1179648, N2 = 389120;
  const int total = N0 + N1 + N2;
  for (int idx = blockIdx.x * 256 + threadIdx.x; idx < total; idx += gridDim.x * 256) {
    if (idx < N0) {
      int ci = idx / 1156, r = idx % 1156;
      int yy = r / 34, xx = r % 34;
      float v = 0.f;
      if (yy >= 1 && yy <= 32 && xx >= 1 && xx <= 32)
        v = tfeat[ci * 1024 + (yy - 1) * 32 + (xx - 1)];
      ws[WS_TFP + idx] = v;
    } else if (idx < N0 + N1) {
      int j = idx - N0;
      int ci = j / 2304, r = j % 2304;
      int co = r / 9, pq = r % 9;
      ws[WS_WT + j] = wtgt[co * 4608 + ci * 9 + pq];
    } else {
      ws[WS_TP + (idx - N0 - N1)] = 0.f;
    }
  }
}

__global__ __launch_bounds__(256) void k1_fold_conv(
    const float* __restrict__ wtpl,    // w_template 16384*4608
    const float* __restrict__ btpl,    // b_template 16384
    const float* __restrict__ wm,      // w_merge_cls 256
    const float* __restrict__ btgt,    // b_target 256
    const float* __restrict__ gamma, const float* __restrict__ beta,
    const float* __restrict__ mean, const float* __restrict__ var,
    float* ws)
{
  __shared__ float wm_l[128];
  __shared__ float red[256];
  const int tid = threadIdx.x;
  const int bid = blockIdx.x;

  if (bid < 256) {
    // ---------------- FOLD path (HBM-bound) ----------------
    const int eh = bid >> 1, half = bid & 1;
    const int e = eh >> 1, h128 = eh & 1;
    if (tid < 128) wm_l[tid] = wm[h128 * 128 + tid];
    __syncthreads();
    if (half == 0) {
      float v = 0.f;
      if (tid < 128) v = wm_l[tid] * btpl[e * 256 + h128 * 128 + tid];
      red[tid] = v;
      __syncthreads();
      for (int s = 128; s > 0; s >>= 1) {
        if (tid < s) red[tid] += red[tid + s];
        __syncthreads();
      }
      if (tid == 0) ws[WS_BF + eh] = red[0];
    }
    float acc[9];
    #pragma unroll
    for (int i = 0; i < 9; i++) acc[i] = 0.f;
    const int col0 = half * 2304 + tid;
    const float* base = wtpl + (size_t)(e * 256 + h128 * 128) * 4608;
    #pragma unroll 4
    for (int cl = 0; cl < 128; cl++) {
      const float wv = wm_l[cl];
      const float* row = base + (size_t)cl * 4608;
      #pragma unroll
      for (int i = 0; i < 9; i++)
        acc[i] = fmaf(wv, row[col0 + 256 * i], acc[i]);
    }
    float* wf = ws + WS_WF;
    #pragma unroll
    for (int i = 0; i < 9; i++)
      wf[(size_t)(col0 + 256 * i) * 128 + eh] = acc[i];
  } else {
    // ---------------- target conv + BN path (VALU-bound) ----------------
    const int cb = bid - 256;
    const int coblk = cb >> 4;            // 16 co-blocks of 16 channels
    const int pxblk = cb & 15;            // 16 row-pair blocks
    const int co0 = coblk * 16;
    const int y0 = pxblk * 2;
    const int wave = tid >> 6, lane = tid & 63;
    const int y = y0 + (lane >> 5), x = lane & 31;
    int coA = co0 + wave * 4;
    coA = __builtin_amdgcn_readfirstlane(coA);   // force scalar weight loads
    const float* tfp = ws + WS_TFP;
    const float* wT = ws + WS_WT;
    const float* tfpc = tfp + y * 34 + x;
    const float* wpc = wT + coA * 9;

    float acc[4] = {0.f, 0.f, 0.f, 0.f};
    float b0[9], b1[9], w0_[36], w1_[36];
    #pragma unroll
    for (int k = 0; k < 9; k++) b0[k] = tfpc[(k / 3) * 34 + (k % 3)];
    #pragma unroll
    for (int k = 0; k < 36; k++) w0_[k] = wpc[k];

    for (int ci = 0; ci < 512; ci += 2) {
      const float* tn = tfpc + (size_t)(ci + 1) * 1156;
      const float* wn = wpc + (size_t)(ci + 1) * 2304;
      #pragma unroll
      for (int k = 0; k < 9; k++) b1[k] = tn[(k / 3) * 34 + (k % 3)];
      #pragma unroll
      for (int k = 0; k < 36; k++) w1_[k] = wn[k];
      #pragma unroll
      for (int c = 0; c < 4; c++)
        #pragma unroll
        for (int k = 0; k < 9; k++)
          acc[c] = fmaf(w0_[c * 9 + k], b0[k], acc[c]);
      if (ci + 2 < 512) {
        const float* t2 = tfpc + (size_t)(ci + 2) * 1156;
        const float* w2 = wpc + (size_t)(ci + 2) * 2304;
        #pragma unroll
        for (int k = 0; k < 9; k++) b0[k] = t2[(k / 3) * 34 + (k % 3)];
        #pragma unroll
        for (int k = 0; k < 36; k++) w0_[k] = w2[k];
      }
      #pragma unroll
      for (int c = 0; c < 4; c++)
        #pragma unroll
        for (int k = 0; k < 9; k++)
          acc[c] = fmaf(w1_[c * 9 + k], b1[k], acc[c]);
    }
    float* tP = ws + WS_TP;
    #pragma unroll
    for (int c = 0; c < 4; c++) {
      const int co = coA + c;
      const float sc = gamma[co] * rsqrtf(var[co] + 1e-5f);
      float t = (acc[c] + btgt[co] - mean[co]) * sc + beta[co];
      t *= 0.1f;                          // fold the 0.1 xcorr factor into t'
      tP[co * 1520 + (y + 3) * 40 + (x + 3)] = t;
    }
  }
}

__global__ __launch_bounds__(256) void k2_z2(
    const float* __restrict__ zfeat,    // template_feat 2*512*49
    float* ws)
{
  __shared__ float Tl[50][144];
  const int tid = threadIdx.x;
  const int n = blockIdx.x >> 5, kc = blockIdx.x & 31;
  const int ci0 = kc * 16;
  // stage im2col rows of the template (zero-padded 3x3 halo), k-local = (ci-ci0)*9+pq
  for (int idx = tid; idx < 7200; idx += 256) {
    const int uv = idx / 144, kk = idx % 144;
    float v = 0.f;
    if (uv < 49) {
      const int u = uv / 7, vv = uv % 7;
      const int ci = ci0 + kk / 9, pq = kk % 9;
      const int p = pq / 3, q = pq % 3;
      const int yy = u + p - 1, xx = vv + q - 1;
      if (yy >= 0 && yy < 7 && xx >= 0 && xx < 7)
        v = zfeat[n * 25088 + ci * 49 + yy * 7 + xx];
    }
    Tl[uv][kk] = v;
  }
  __syncthreads();
  const int ehq = tid & 31, uvg = tid >> 5;
  const int eh0 = ehq * 4;
  const int uv0 = (uvg == 0) ? 0 : uvg * 6 + 1;
  const float* wf = ws + WS_WF;
  float4 acc[7];
  #pragma unroll
  for (int i = 0; i < 7; i++) acc[i] = make_float4(0.f, 0.f, 0.f, 0.f);
  for (int g = 0; g < 36; g++) {
    const float* wr = wf + (size_t)(ci0 * 9 + g * 4) * 128 + eh0;
    const float4 wv0 = *(const float4*)(wr);
    const float4 wv1 = *(const float4*)(wr + 128);
    const float4 wv2 = *(const float4*)(wr + 256);
    const float4 wv3 = *(const float4*)(wr + 384);
    #pragma unroll
    for (int uu = 0; uu < 7; uu++) {
      const float4 t4 = *(const float4*)(&Tl[uv0 + uu][g * 4]);
      acc[uu].x = fmaf(t4.x, wv0.x, fmaf(t4.y, wv1.x, fmaf(t4.z, wv2.x, fmaf(t4.w, wv3.x, acc[uu].x))));
      acc[uu].y = fmaf(t4.x, wv0.y, fmaf(t4.y, wv1.y, fmaf(t4.z, wv2.y, fmaf(t4.w, wv3.y, acc[uu].y))));
      acc[uu].z = fmaf(t4.x, wv0.z, fmaf(t4.y, wv1.z, fmaf(t4.z, wv2.z, fmaf(t4.w, wv3.z, acc[uu].z))));
      acc[uu].w = fmaf(t4.x, wv0.w, fmaf(t4.y, wv1.w, fmaf(t4.z, wv2.w, fmaf(t4.w, wv3.w, acc[uu].w))));
    }
  }
  float* z2p = ws + WS_Z2P;
  #pragma unroll
  for (int uu = 0; uu < 7; uu++) {
    const int uv = uv0 + uu;
    if (uv <= 48)   // overlapping uv written twice with identical values (benign)
      *(float4*)(z2p + ((size_t)((n * 32 + kc) * 49 + uv)) * 128 + eh0) = acc[uu];
  }
}

__global__ __launch_bounds__(128) void k3_merged(float* ws)
{
  __shared__ float Z2s[16][7][8];
  const int tid = threadIdx.x;
  const int bid = blockIdx.x;
  const int n = bid >> 7, rest = bid & 127;
  const int ec = rest >> 4, hq = rest & 15;
  const int c0 = ec * 16, h0 = hq * 2;
  const float* z2p = ws + WS_Z2P;
  const float* bf = ws + WS_BF;
  // reduce the 32 K-split partials (+ Bfold) for this block's 16 channels
  for (int idx = tid; idx < 784; idx += 128) {
    const int cl = idx & 15, uv = idx >> 4;
    float s = bf[c0 + cl];
    const float* p = z2p + (size_t)(n * 1568 + uv) * 128 + (c0 + cl);
    #pragma unroll 8
    for (int kc = 0; kc < 32; kc++) s += p[(size_t)kc * 6272];
    Z2s[cl][uv / 7][uv % 7] = s;
  }
  for (int idx = tid; idx < 112; idx += 128)
    Z2s[idx / 7][idx % 7][7] = 0.f;   // 8th lane of v-dim = 0
  __syncthreads();

  const int e = tid >> 4, row = (tid >> 3) & 1, wq = tid & 7;
  const int w0 = wq * 4;
  const float* tP = ws + WS_TP;
  float acc[4] = {0.f, 0.f, 0.f, 0.f};
  #pragma unroll
  for (int h128 = 0; h128 < 2; h128++) {
    const int cl = 2 * e + h128;
    const float* tc = tP + (size_t)(128 * n + c0 + cl) * 1520;
    #pragma unroll
    for (int u = 0; u < 7; u++) {
      const float* trow = tc + (h0 + row + u) * 40 + w0;
      float tw[12];
      *(float4*)&tw[0] = *(const float4*)(trow);
      *(float4*)&tw[4] = *(const float4*)(trow + 4);
      *(float4*)&tw[8] = *(const float4*)(trow + 8);
      float z[8];
      *(float4*)&z[0] = *(const float4*)&Z2s[cl][u][0];
      *(float4*)&z[4] = *(const float4*)&Z2s[cl][u][4];
      #pragma unroll
      for (int px = 0; px < 4; px++)
        #pragma unroll
        for (int v = 0; v < 8; v++)
          acc[px] = fmaf(z[v], tw[px + v], acc[px]);
    }
  }
  float* mrg = ws + WS_MRG;
  *(float4*)(mrg + (size_t)(((n * 64 + ec * 8 + e) * 32) + h0 + row) * 32 + w0) =
      make_float4(acc[0], acc[1], acc[2], acc[3]);
}

__global__ __launch_bounds__(256) void k4_heads(
    const float* __restrict__ cb,
    const float* __restrict__ wcls, const float* __restrict__ bcls,
    const float* __restrict__ wbox, const float* __restrict__ bbox,
    float* ws, float* __restrict__ out)
{
  __shared__ float mrg_l[32][66];   // [w][e], padded for bank spread
  __shared__ float wcb_l[54][64];
  __shared__ float bias_l[54];
  __shared__ float logits[18][32];
  const int tid = threadIdx.x;
  const int n = blockIdx.x >> 5, h = blockIdx.x & 31;
  const float* mrg = ws + WS_MRG;
  for (int idx = tid; idx < 2048; idx += 256) {
    const int e = idx >> 5, w = idx & 31;
    mrg_l[w][e] = mrg[(size_t)(((n * 64 + e) * 32) + h) * 32 + w] + cb[e];
  }
  for (int idx = tid; idx < 3456; idx += 256) {
    const int ch = idx >> 6, e = idx & 63;
    wcb_l[ch][e] = (ch < 18) ? wcls[ch * 64 + e] : wbox[(ch - 18) * 64 + e];
  }
  if (tid < 54) bias_l[tid] = (tid < 18) ? bcls[tid] : bbox[tid - 18];
  __syncthreads();

  const int w = tid & 31, chg = tid >> 5;
  const int cnt = (chg < 6) ? 7 : 6;
  float acc[7] = {0.f, 0.f, 0.f, 0.f, 0.f, 0.f, 0.f};
  for (int e2 = 0; e2 < 32; e2++) {
    const float2 m2 = *(const float2*)&mrg_l[w][e2 * 2];
    #pragma unroll
    for (int i = 0; i < 7; i++) {
      if (i < cnt) {
        const int ch = chg + 8 * i;
        const float2 wv = *(const float2*)&wcb_l[ch][e2 * 2];
        acc[i] = fmaf(m2.x, wv.x, acc[i]);
        acc[i] = fmaf(m2.y, wv.y, acc[i]);
      }
    }
  }
  #pragma unroll
  for (int i = 0; i < 7; i++) {
    if (i < cnt) {
      const int ch = chg + 8 * i;
      const float v = acc[i] + bias_l[ch];
      if (ch < 18) logits[ch][w] = v;
      else out[36864 + n * 36864 + (ch - 18) * 1024 + h * 32 + w] = v;
    }
  }
  __syncthreads();
  for (int idx = tid; idx < 576; idx += 256) {
    const int ch = idx >> 5, w2 = idx & 31;
    const float a = logits[ch][w2];
    const float b = logits[(ch + 9) % 18][w2];
    const float m = fmaxf(a, b);
    const float ea = expf(a - m), eb = expf(b - m);
    out[n * 18432 + ch * 1024 + h * 32 + w2] = ea / (ea + eb);
  }
}

extern "C" void kernel_launch(void* const* d_in, const int* in_sizes, int n_in,
                              void* d_out, int out_size, void* d_ws, size_t ws_size,
                              hipStream_t stream) {
  (void)in_sizes; (void)n_in; (void)out_size; (void)ws_size;
  const float* target_feat   = (const float*)d_in[0];
  const float* template_feat = (const float*)d_in[1];
  const float* w_target      = (const float*)d_in[2];
  const float* b_target      = (const float*)d_in[3];
  const float* bn_gamma      = (const float*)d_in[4];
  const float* bn_beta       = (const float*)d_in[5];
  const float* bn_mean       = (const float*)d_in[6];
  const float* bn_var        = (const float*)d_in[7];
  const float* w_template    = (const float*)d_in[8];
  const float* b_template    = (const float*)d_in[9];
  const float* w_merge       = (const float*)d_in[10];
  const float* corr_bias     = (const float*)d_in[11];
  const float* w_cls         = (const float*)d_in[12];
  const float* b_cls         = (const float*)d_in[13];
  const float* w_box         = (const float*)d_in[14];
  const float* b_box         = (const float*)d_in[15];
  float* ws = (float*)d_ws;
  float* out = (float*)d_out;

  hipLaunchKernelGGL(k0_prep, dim3(2048), dim3(256), 0, stream,
                     target_feat, w_target, ws);
  hipLaunchKernelGGL(k1_fold_conv, dim3(512), dim3(256), 0, stream,
                     w_template, b_template, w_merge, b_target,
                     bn_gamma, bn_beta, bn_mean, bn_var, ws);
  hipLaunchKernelGGL(k2_z2, dim3(64), dim3(256), 0, stream,
                     template_feat, ws);
  hipLaunchKernelGGL(k3_merged, dim3(256), dim3(128), 0, stream, ws);
  hipLaunchKernelGGL(k4_heads, dim3(64), dim3(256), 0, stream,
                     corr_bias, w_cls, b_cls, w_box, b_box, ws, out);
}